// Round 7
// baseline (180.682 us; speedup 1.0000x reference)
//
#include <hip/hip_runtime.h>

#ifndef __has_builtin
#define __has_builtin(x) 0
#endif

#if __has_builtin(__builtin_amdgcn_exp2f)
#define EXP2F(x) __builtin_amdgcn_exp2f(x)
#else
#define EXP2F(x) exp2f(x)
#endif

#if __has_builtin(__builtin_amdgcn_rcpf)
#define RCPF(x) __builtin_amdgcn_rcpf(x)
#else
#define RCPF(x) (1.0f / (x))
#endif

namespace {

constexpr int kB = 65536;
constexpr int kT = 50;
constexpr int kI = 2;
constexpr int kH = 20;
constexpr int kO = 2;
constexpr int kGB = 64;    // batch elements per block
// chunk = 4 timesteps = 320B per element; 12 chunks + 2-step tail
// LDS: 2 bufs x 64 elem x 84 floats (pad 80->84 => 2-way bank = free)
constexpr int kES  = 84;                 // element stride in floats
constexpr int kBUF = kGB * kES;          // 5376 floats per buffer
constexpr int kBUF_B = kBUF * 4;         // 21504 bytes

__device__ __forceinline__ float fast_tanh(float v) {
    // tanh(v) = 1 - 2/(exp(2v)+1); v_exp_f32 saturates so no clamp needed
    const float p = EXP2F(v * 2.8853900817779268f);
    return fmaf(-2.0f, RCPF(p + 1.0f), 1.0f);
}

// Intra-quad lane exchange via DPP quad_perm (pure VALU).
// xor1: [1,0,3,2]=0xB1  xor2: [2,3,0,1]=0x4E  xor3: [3,2,1,0]=0x1B
#if __has_builtin(__builtin_amdgcn_mov_dpp)
template <int CTRL>
__device__ __forceinline__ float fqp(float v) {
    return __int_as_float(
        __builtin_amdgcn_mov_dpp(__float_as_int(v), CTRL, 0xF, 0xF, true));
}
#else
template <int CTRL>
__device__ __forceinline__ float fqp(float v) {
    constexpr int d = (CTRL == 0xB1) ? 1 : (CTRL == 0x4E) ? 2 : 3;
    return __shfl_xor(v, d);
}
#endif

// load a 5x dwordx4 staging set (wave covers its 16 elements' 320B runs;
// 20 consecutive lanes read ONE element's contiguous 320B => DRAM row bursts)
#define LOADSET(S, c)                                                  \
    {                                                                  \
        S##0 = *(const float4*)(mblk + so0 + (c) * 320);               \
        S##1 = *(const float4*)(mblk + so1 + (c) * 320);               \
        S##2 = *(const float4*)(mblk + so2 + (c) * 320);               \
        S##3 = *(const float4*)(mblk + so3 + (c) * 320);               \
        S##4 = *(const float4*)(mblk + so4 + (c) * 320);               \
    }

#define WRITESET(S, bufbyte)                                           \
    {                                                                  \
        *(float4*)(smb + (bufbyte) + lo0) = S##0;                      \
        *(float4*)(smb + (bufbyte) + lo1) = S##1;                      \
        *(float4*)(smb + (bufbyte) + lo2) = S##2;                      \
        *(float4*)(smb + (bufbyte) + lo3) = S##3;                      \
        *(float4*)(smb + (bufbyte) + lo4) = S##4;                      \
    }

// 4 threads (one quad) per batch element; thread sub owns hidden rows
// 4*i+sub. W_hh in registers, columns permuted for DPP gather:
//   w[i][r][d] = W_hh[(4i+sub)*20 + (4r + (sub^d))]
// Mask: wave-private LDS double-buffer, register-relay staged (counted
// vmcnt from compiler, NO block barriers, NO global_load_lds aliasing).
__global__ __launch_bounds__(256)
__attribute__((amdgpu_waves_per_eu(2, 2)))
void dprnn_kernel(
    const float* __restrict__ x, const float* __restrict__ W_ih,
    const float* __restrict__ W_hh, const float* __restrict__ b_ih,
    const float* __restrict__ b_hh, const float* __restrict__ W_out,
    const float* __restrict__ b_out, const float* __restrict__ mask,
    float* __restrict__ out)
{
    __shared__ __align__(16) float sm[2 * kBUF];   // 43008 B
    char* smb = (char*)sm;

    const int tidx = threadIdx.x;
    const int gl   = tidx >> 2;          // element index within block 0..63
    const int sub  = tidx & 3;           // quarter of H owned
    const int Wv   = tidx >> 6;          // wave 0..3 (owns elems 16W..16W+15)
    const int l    = tidx & 63;          // lane
    const size_t g = (size_t)blockIdx.x * kGB + gl;

    // ---- weights into registers (column-permuted for DPP gather) ----
    float w[5][5][4];
    float wi0[5], wi1[5], bia[5], wo0[5], wo1[5];
#pragma unroll
    for (int i = 0; i < 5; ++i) {
        const int row = 4 * i + sub;
#pragma unroll
        for (int r = 0; r < 5; ++r)
#pragma unroll
            for (int d = 0; d < 4; ++d)
                w[i][r][d] = W_hh[row * kH + 4 * r + (sub ^ d)];
        wi0[i] = W_ih[row * kI + 0];
        wi1[i] = W_ih[row * kI + 1];
        bia[i] = b_ih[row] + b_hh[row];
        wo0[i] = W_out[row];
        wo1[i] = W_out[kH + row];
    }
    const float bo0 = b_out[0];
    const float bo1 = b_out[1];

    // ---- staging address constants (per thread, computed once) ----
    // main chunks: 320 pieces of 16B per wave; piece p: elem=p/20, off=p%20
    const char* mblk = (const char*)mask + (size_t)blockIdx.x * kGB * 4000;
    uint32_t so0, so1, so2, so3, so4, lo0, lo1, lo2, lo3, lo4;
    {
        int p, e, o;
        p = 0 * 64 + l; e = p / 20; o = p - 20 * e;
        so0 = (Wv * 16 + e) * 4000 + o * 16; lo0 = (Wv * 16 + e) * 336 + o * 16;
        p = 1 * 64 + l; e = p / 20; o = p - 20 * e;
        so1 = (Wv * 16 + e) * 4000 + o * 16; lo1 = (Wv * 16 + e) * 336 + o * 16;
        p = 2 * 64 + l; e = p / 20; o = p - 20 * e;
        so2 = (Wv * 16 + e) * 4000 + o * 16; lo2 = (Wv * 16 + e) * 336 + o * 16;
        p = 3 * 64 + l; e = p / 20; o = p - 20 * e;
        so3 = (Wv * 16 + e) * 4000 + o * 16; lo3 = (Wv * 16 + e) * 336 + o * 16;
        p = 4 * 64 + l; e = p / 20; o = p - 20 * e;
        so4 = (Wv * 16 + e) * 4000 + o * 16; lo4 = (Wv * 16 + e) * 336 + o * 16;
    }
    // tail (t=48,49): 160 pieces; piece p: elem=p/10, off=p%10 (clamped)
    uint32_t tso0, tso1, tso2, tlo0, tlo1, tlo2;
    {
        int p, e, o;
        p = 0 * 64 + l;                   e = p / 10; o = p - 10 * e;
        tso0 = (Wv * 16 + e) * 4000 + 3840 + o * 16; tlo0 = (Wv * 16 + e) * 336 + o * 16;
        p = 1 * 64 + l;                   e = p / 10; o = p - 10 * e;
        tso1 = (Wv * 16 + e) * 4000 + 3840 + o * 16; tlo1 = (Wv * 16 + e) * 336 + o * 16;
        p = 2 * 64 + l; p = (p > 159) ? 159 : p; e = p / 10; o = p - 10 * e;
        tso2 = (Wv * 16 + e) * 4000 + 3840 + o * 16; tlo2 = (Wv * 16 + e) * 336 + o * 16;
    }

    const float* xp = x + g * (kT * kI);
    float* op = out + g * (kT * kO);
    const int mrd = gl * kES + sub;      // consume base (floats, +buf+imm)

    float h[5] = {0.f, 0.f, 0.f, 0.f, 0.f};

    // one RNN step; LDS mask at sm[mrd + off + 4r], off compile-time const
    auto step = [&](int off, float x0, float x1, int t) {
        const float m0_ = sm[mrd + off];
        const float m1_ = sm[mrd + off + 4];
        const float m2_ = sm[mrd + off + 8];
        const float m3_ = sm[mrd + off + 12];
        const float m4_ = sm[mrd + off + 16];
        float acc[5];
#pragma unroll
        for (int i = 0; i < 5; ++i)
            acc[i] = fmaf(wi0[i], x0, fmaf(wi1[i], x1, bia[i]));
#pragma unroll
        for (int r = 0; r < 5; ++r) {
            const float v0 = h[r];
            const float v1 = fqp<0xB1>(h[r]);
            const float v2 = fqp<0x4E>(h[r]);
            const float v3 = fqp<0x1B>(h[r]);
#pragma unroll
            for (int i = 0; i < 5; ++i) {
                acc[i] = fmaf(w[i][r][0], v0, acc[i]);
                acc[i] = fmaf(w[i][r][1], v1, acc[i]);
                acc[i] = fmaf(w[i][r][2], v2, acc[i]);
                acc[i] = fmaf(w[i][r][3], v3, acc[i]);
            }
        }
        const float mm[5] = {m0_, m1_, m2_, m3_, m4_};
        float p0 = 0.f, p1 = 0.f;
#pragma unroll
        for (int i = 0; i < 5; ++i) {
            const float hn = fast_tanh(acc[i]);
            h[i] = hn;
            const float dm = hn * mm[i];
            p0 = fmaf(dm, wo0[i], p0);
            p1 = fmaf(dm, wo1[i], p1);
        }
        p0 += fqp<0xB1>(p0);
        p0 += fqp<0x4E>(p0);
        p1 += fqp<0xB1>(p1);
        p1 += fqp<0x4E>(p1);
        if (sub == 0)
            *(float2*)(op + t * kO) = make_float2(p0 + bo0, p1 + bo1);
    };

    // ---- staging register sets ----
    float4 A0, A1, A2, A3, A4;
    float4 B0, B1, B2, B3, B4;
    float4 Ta, Tb, Tc, xT;

    // prologue: A<-c0, B<-c1; write c0 -> buf0; A<-c2
    LOADSET(A, 0);
    LOADSET(B, 1);
    float4 xE0 = *(const float4*)(xp);
    float4 xE1 = *(const float4*)(xp + 4);
    float4 xO0 = *(const float4*)(xp + 8);
    float4 xO1 = *(const float4*)(xp + 12);
    WRITESET(A, 0);
    LOADSET(A, 2);

#pragma unroll 1
    for (int k = 0; k < 12; ++k) {
        if ((k & 1) == 0) {
            // even chunk: consume buf0; B holds odd chunk k+1 -> buf1
            WRITESET(B, kBUF_B);
            if (k <= 8) LOADSET(B, (k + 3));
            step(0,  xE0.x, xE0.y, 4 * k);
            step(20, xE0.z, xE0.w, 4 * k + 1);
            step(40, xE1.x, xE1.y, 4 * k + 2);
            step(60, xE1.z, xE1.w, 4 * k + 3);
            if (k <= 8) {
                xE0 = *(const float4*)(xp + 8 * (k + 2));
                xE1 = *(const float4*)(xp + 8 * (k + 2) + 4);
            }
        } else {
            // odd chunk: consume buf1; A holds even chunk k+1 -> buf0
            if (k == 11) {
                *(float4*)(smb + tlo0) = Ta;
                *(float4*)(smb + tlo1) = Tb;
                *(float4*)(smb + tlo2) = Tc;
            } else {
                WRITESET(A, 0);
            }
            if (k <= 8) LOADSET(A, (k + 3));
            if (k == 9) {
                Ta = *(const float4*)(mblk + tso0);
                Tb = *(const float4*)(mblk + tso1);
                Tc = *(const float4*)(mblk + tso2);
                xT = *(const float4*)(xp + 96);
            }
            step(kBUF,      xO0.x, xO0.y, 4 * k);
            step(kBUF + 20, xO0.z, xO0.w, 4 * k + 1);
            step(kBUF + 40, xO1.x, xO1.y, 4 * k + 2);
            step(kBUF + 60, xO1.z, xO1.w, 4 * k + 3);
            if (k <= 9) {
                xO0 = *(const float4*)(xp + 8 * (k + 2));
                xO1 = *(const float4*)(xp + 8 * (k + 2) + 4);
            }
        }
    }

    // tail: t = 48, 49 from buf0 (written at k=11)
    step(0,  xT.x, xT.y, 48);
    step(20, xT.z, xT.w, 49);
}

}  // namespace

extern "C" void kernel_launch(void* const* d_in, const int* in_sizes, int n_in,
                              void* d_out, int out_size, void* d_ws, size_t ws_size,
                              hipStream_t stream) {
    const float* x     = (const float*)d_in[0];
    const float* W_ih  = (const float*)d_in[1];
    const float* W_hh  = (const float*)d_in[2];
    const float* b_ih  = (const float*)d_in[3];
    const float* b_hh  = (const float*)d_in[4];
    const float* W_out = (const float*)d_in[5];
    const float* b_out = (const float*)d_in[6];
    const float* mask  = (const float*)d_in[7];
    float* out = (float*)d_out;

    dim3 block(256);
    dim3 grid(kB / kGB);                 // 1024 blocks
    dprnn_kernel<<<grid, block, 0, stream>>>(x, W_ih, W_hh, b_ih, b_hh,
                                             W_out, b_out, mask, out);
}